// Round 2
// baseline (115.058 us; speedup 1.0000x reference)
//
#include <hip/hip_runtime.h>

#define B_DIM 4
#define C_DIM 256
#define N_DIM 4096   // 64*64
#define INTER 64

// workspace layout (float offsets) — total ~37 KFloats ~ 150 KB
#define EQ_OFF   0
#define EK_OFF   (B_DIM*N_DIM)            // 16384
#define SX_OFF   (2*B_DIM*N_DIM)          // 32768
#define SXE_OFF  (SX_OFF + B_DIM*C_DIM)   // 33792
#define UQ_OFF   (SXE_OFF + B_DIM*C_DIM)  // 34816
#define UK_OFF   (UQ_OFF + C_DIM)         // 35072
#define CQ_OFF   (UK_OFF + C_DIM)         // 35328
#define CK_OFF   (CQ_OFF + 1)             // 35329
#define SEQ_OFF  (CK_OFF + 1)             // 35330
#define SV_OFF   (SEQ_OFF + B_DIM)        // 35334
#define SVE_OFF  (SV_OFF + B_DIM*C_DIM)   // 36358

__device__ inline float wave_red_sum(float v) {
    #pragma unroll
    for (int off = 32; off > 0; off >>= 1) v += __shfl_down(v, off, 64);
    return v;
}

// K0: uq[c] = sum_o Wc[o]*Wq[o,c]; uk[c] = sum_o Wc[64+o]*Wk[o,c]; cq = wq.bq; ck = wk.bk
__global__ void k_prep(const float* __restrict__ Wq, const float* __restrict__ bq,
                       const float* __restrict__ Wk, const float* __restrict__ bk,
                       const float* __restrict__ Wc, float* __restrict__ ws) {
    int c = threadIdx.x;  // 256 threads
    float uq = 0.f, uk = 0.f;
    #pragma unroll 8
    for (int o = 0; o < INTER; ++o) {
        uq = fmaf(Wc[o],         Wq[o * C_DIM + c], uq);
        uk = fmaf(Wc[INTER + o], Wk[o * C_DIM + c], uk);
    }
    ws[UQ_OFF + c] = uq;
    ws[UK_OFF + c] = uk;
    if (c == 0) { float s = 0.f; for (int o = 0; o < INTER; ++o) s = fmaf(Wc[o], bq[o], s); ws[CQ_OFF] = s; }
    if (c == 1) { float s = 0.f; for (int o = 0; o < INTER; ++o) s = fmaf(Wc[INTER + o], bk[o], s); ws[CK_OFF] = s; }
}

// K1: eq[b,n] = sum_c uq[c]*x[b,c,n] + cq ; ek likewise.
// grid: (N/64, B), block 256 = 4 waves. Wave w reduces channels [64w,64w+64) for the
// block's 64 consecutive n (lane = n). LDS cross-wave reduce; no atomics, no init needed.
__global__ void k_eqek(const float* __restrict__ x, const float* __restrict__ ws_ro,
                       float* __restrict__ ws) {
    const int lane  = threadIdx.x & 63;
    const int wid   = threadIdx.x >> 6;          // 0..3
    const int n     = blockIdx.x * 64 + lane;
    const int b     = blockIdx.y;
    const int cbase = wid * 64;
    const float* xp = x + ((size_t)b * C_DIM + cbase) * N_DIM + n;
    const float* uq = ws_ro + UQ_OFF + cbase;
    const float* uk = ws_ro + UK_OFF + cbase;
    float aq = 0.f, ak = 0.f;
    #pragma unroll 16
    for (int c = 0; c < 64; ++c) {
        float xv = xp[(size_t)c * N_DIM];        // lanes -> consecutive n : coalesced 256B
        aq = fmaf(uq[c], xv, aq);
        ak = fmaf(uk[c], xv, ak);
    }
    __shared__ float sq[4][64], sk[4][64];
    sq[wid][lane] = aq;
    sk[wid][lane] = ak;
    __syncthreads();
    if (wid == 0) {
        float tq = sq[0][lane] + sq[1][lane] + sq[2][lane] + sq[3][lane] + ws_ro[CQ_OFF];
        float tk = sk[0][lane] + sk[1][lane] + sk[2][lane] + sk[3][lane] + ws_ro[CK_OFF];
        ws[EQ_OFF + b * N_DIM + n] = tq;
        ws[EK_OFF + b * N_DIM + n] = tk;
    }
}

// K2: per (b,c): Sx = sum_n x[b,c,n]; Sxe = sum_n x[b,c,n]*eq[b,n]; (c==0) Seq[b] = sum_n eq[b,n].
// grid: B*C blocks of 256 threads, float4 loads.
__global__ void k_rowsums(const float* __restrict__ x, const float* __restrict__ ws_ro,
                          float* __restrict__ ws) {
    const int bc = blockIdx.x;
    const int b  = bc >> 8;           // / C_DIM
    const int c  = bc & (C_DIM - 1);
    const float4* xp = (const float4*)(x + (size_t)bc * N_DIM);
    const float4* eq = (const float4*)(ws_ro + EQ_OFF + (size_t)b * N_DIM);
    float sx = 0.f, sxe = 0.f, se = 0.f;
    #pragma unroll
    for (int i = threadIdx.x; i < N_DIM / 4; i += 256) {
        float4 xv = xp[i];
        float4 e  = eq[i];
        sx += xv.x + xv.y + xv.z + xv.w;
        sxe = fmaf(xv.x, e.x, sxe); sxe = fmaf(xv.y, e.y, sxe);
        sxe = fmaf(xv.z, e.z, sxe); sxe = fmaf(xv.w, e.w, sxe);
        se += e.x + e.y + e.z + e.w;
    }
    sx  = wave_red_sum(sx);
    sxe = wave_red_sum(sxe);
    se  = wave_red_sum(se);
    __shared__ float red[3][4];
    const int wid = threadIdx.x >> 6, lane = threadIdx.x & 63;
    if (lane == 0) { red[0][wid] = sx; red[1][wid] = sxe; red[2][wid] = se; }
    __syncthreads();
    if (threadIdx.x == 0) {
        ws[SX_OFF + bc]  = red[0][0] + red[0][1] + red[0][2] + red[0][3];
        ws[SXE_OFF + bc] = red[1][0] + red[1][1] + red[1][2] + red[1][3];
        if (c == 0)
            ws[SEQ_OFF + b] = red[2][0] + red[2][1] + red[2][2] + red[2][3];
    }
}

// K3: Sv[b,c]  = sum_c' Wv[c,c']*Sx[b,c']  + N*bv[c]
//     Sve[b,c] = sum_c' Wv[c,c']*Sxe[b,c'] + bv[c]*Seq[b]
// grid: B blocks of 256 threads (thread = c).
__global__ void k_sv(const float* __restrict__ Wv, const float* __restrict__ bv,
                     const float* __restrict__ ws_ro, float* __restrict__ ws) {
    const int b = blockIdx.x;
    const int c = threadIdx.x;
    __shared__ float sSx[C_DIM], sSxe[C_DIM];
    sSx[c]  = ws_ro[SX_OFF + b * C_DIM + c];
    sSxe[c] = ws_ro[SXE_OFF + b * C_DIM + c];
    __syncthreads();
    const float* wv = Wv + (size_t)c * C_DIM;
    float sv = 0.f, sve = 0.f;
    #pragma unroll 8
    for (int cc = 0; cc < C_DIM; ++cc) {
        float w = wv[cc];
        sv  = fmaf(w, sSx[cc],  sv);
        sve = fmaf(w, sSxe[cc], sve);
    }
    ws[SV_OFF + b * C_DIM + c]  = sv + (float)N_DIM * bv[c];
    ws[SVE_OFF + b * C_DIM + c] = sve + bv[c] * ws_ro[SEQ_OFF + b];
}

// K4: out[b,c,m] = ginv*Sve[b,c] + ginv*Sv[b,c]*ek[b,m] + x[b,c,m], float4 over m.
__global__ void k_out(const float* __restrict__ x, const float* __restrict__ ws,
                      const float* __restrict__ gamma, float* __restrict__ out) {
    const float ginv = gamma[0] / (float)N_DIM;
    const size_t total4 = (size_t)B_DIM * C_DIM * N_DIM / 4;
    for (size_t i = (size_t)blockIdx.x * blockDim.x + threadIdx.x; i < total4;
         i += (size_t)gridDim.x * blockDim.x) {
        const size_t e = i * 4;
        const int m  = (int)(e & (N_DIM - 1));       // 4-aligned
        const int bc = (int)(e >> 12);               // / N_DIM
        const int b  = bc >> 8;                      // / C_DIM
        const float4 xv  = ((const float4*)x)[i];
        const float4 ekv = *(const float4*)(ws + EK_OFF + (size_t)b * N_DIM + m);
        const float t1 = ws[SV_OFF + bc]  * ginv;
        const float t2 = ws[SVE_OFF + bc] * ginv;
        float4 o;
        o.x = fmaf(ekv.x, t1, t2) + xv.x;
        o.y = fmaf(ekv.y, t1, t2) + xv.y;
        o.z = fmaf(ekv.z, t1, t2) + xv.z;
        o.w = fmaf(ekv.w, t1, t2) + xv.w;
        ((float4*)out)[i] = o;
    }
}

extern "C" void kernel_launch(void* const* d_in, const int* in_sizes, int n_in,
                              void* d_out, int out_size, void* d_ws, size_t ws_size,
                              hipStream_t stream) {
    const float* x     = (const float*)d_in[0];
    const float* Wq    = (const float*)d_in[1];
    const float* bq    = (const float*)d_in[2];
    const float* Wk    = (const float*)d_in[3];
    const float* bk    = (const float*)d_in[4];
    const float* Wc    = (const float*)d_in[5];
    const float* Wv    = (const float*)d_in[6];
    const float* bv    = (const float*)d_in[7];
    const float* gamma = (const float*)d_in[8];
    float* out = (float*)d_out;
    float* ws  = (float*)d_ws;

    k_prep<<<1, 256, 0, stream>>>(Wq, bq, Wk, bk, Wc, ws);

    dim3 g1(N_DIM / 64, B_DIM);                                // 64 x 4 = 256 blocks
    k_eqek<<<g1, 256, 0, stream>>>(x, ws, ws);

    k_rowsums<<<B_DIM * C_DIM, 256, 0, stream>>>(x, ws, ws);   // 1024 blocks

    k_sv<<<B_DIM, 256, 0, stream>>>(Wv, bv, ws, ws);

    k_out<<<2048, 256, 0, stream>>>(x, ws, gamma, out);
}

// Round 3
// 104.840 us; speedup vs baseline: 1.0975x; 1.0975x over previous
//
#include <hip/hip_runtime.h>

#define B_DIM 4
#define C_DIM 256
#define N_DIM 4096   // 64*64
#define INTER 64
#define LDS_PAD 68   // row stride (floats): 68*4=272 B, 16B-aligned for b128 ops

// workspace layout (float offsets)
#define EK_OFF   0                         // B*N        = 16384
#define PSEQ_OFF 16384                     // B*64       = 256
#define PSX_OFF  16640                     // B*64*C     = 65536
#define PSXE_OFF 82176                     // B*64*C     = 65536
#define SV_OFF   147712                    // B*C        = 1024
#define SVE_OFF  148736                    // B*C        = 1024

__device__ inline float wave_red_sum(float v) {
    #pragma unroll
    for (int off = 32; off > 0; off >>= 1) v += __shfl_down(v, off, 64);
    return v;
}

// KA: per (n-block, b): stage x-tile [256 c][64 n] in LDS once, then
//  (1) uq/uk collapse (redundant per block, L2-cached),
//  (2) eq/ek for the 64 n's (write ek; eq stays in LDS; partial Seq),
//  (3) per-channel partial Sx/Sxe over the 64 n's (reusing the LDS tile).
__global__ __launch_bounds__(256) void k_fuse(
        const float* __restrict__ x,
        const float* __restrict__ Wq, const float* __restrict__ bq,
        const float* __restrict__ Wk, const float* __restrict__ bk,
        const float* __restrict__ Wc, float* __restrict__ ws) {
    __shared__ float xt[C_DIM][LDS_PAD];   // ~68 KB
    __shared__ float uqs[C_DIM], uks[C_DIM];
    __shared__ float sq[4][64], sk[4][64];
    __shared__ float eq_s[64];
    __shared__ float cqk[2];
    const int t  = threadIdx.x;
    const int nb = blockIdx.x;             // 0..63
    const int b  = blockIdx.y;             // 0..3
    const int n0 = nb * 64;

    // (1) uq[c] = wq^T Wq[:,c], uk[c] = wk^T Wk[:,c]
    {
        float uq = 0.f, uk = 0.f;
        #pragma unroll 8
        for (int o = 0; o < INTER; ++o) {
            uq = fmaf(Wc[o],         Wq[o * C_DIM + t], uq);
            uk = fmaf(Wc[INTER + o], Wk[o * C_DIM + t], uk);
        }
        uqs[t] = uq; uks[t] = uk;
        if (t == 0) { float s = 0.f; for (int o = 0; o < INTER; ++o) s = fmaf(Wc[o], bq[o], s); cqk[0] = s; }
        if (t == 1) { float s = 0.f; for (int o = 0; o < INTER; ++o) s = fmaf(Wc[INTER + o], bk[o], s); cqk[1] = s; }
    }

    // stage x-tile: 256 channels x 64 n, float4 loads (coalesced 1 KB/wave-instr)
    const float4* x4 = (const float4*)x;
    #pragma unroll
    for (int i = 0; i < 16; ++i) {
        const int f = i * 256 + t;
        const int c = f >> 4, q = f & 15;
        float4 v = x4[((size_t)b * C_DIM + c) * (N_DIM / 4) + (n0 >> 2) + q];
        *(float4*)&xt[c][4 * q] = v;
    }
    __syncthreads();

    // (2) eq/ek: wave w reduces channels [64w,64w+64) for n = n0 + lane
    const int w = t >> 6, l = t & 63;
    {
        float aq = 0.f, ak = 0.f;
        const int cb = w * 64;
        #pragma unroll 16
        for (int c = 0; c < 64; ++c) {
            float xv = xt[cb + c][l];      // banks spread over l: conflict-free
            aq = fmaf(uqs[cb + c], xv, aq);
            ak = fmaf(uks[cb + c], xv, ak);
        }
        sq[w][l] = aq; sk[w][l] = ak;
    }
    __syncthreads();
    if (w == 0) {
        float tq = sq[0][l] + sq[1][l] + sq[2][l] + sq[3][l] + cqk[0];
        float tk = sk[0][l] + sk[1][l] + sk[2][l] + sk[3][l] + cqk[1];
        ws[EK_OFF + b * N_DIM + n0 + l] = tk;
        eq_s[l] = tq;
        float se = wave_red_sum(tq);
        if (l == 0) ws[PSEQ_OFF + b * 64 + nb] = se;
    }
    __syncthreads();

    // (3) partial Sx/Sxe for channel c = t over this block's 64 n's
    {
        float sx = 0.f, sxe = 0.f;
        const float4* row = (const float4*)&xt[t][0];
        const float4* ev  = (const float4*)&eq_s[0];
        #pragma unroll
        for (int i = 0; i < 16; ++i) {
            float4 xv = row[i];
            float4 e  = ev[i];
            sx += xv.x + xv.y + xv.z + xv.w;
            sxe = fmaf(xv.x, e.x, sxe); sxe = fmaf(xv.y, e.y, sxe);
            sxe = fmaf(xv.z, e.z, sxe); sxe = fmaf(xv.w, e.w, sxe);
        }
        ws[PSX_OFF  + (size_t)(b * 64 + nb) * C_DIM + t] = sx;
        ws[PSXE_OFF + (size_t)(b * 64 + nb) * C_DIM + t] = sxe;
    }
}

// KB: reduce the 64 per-block partials, then Sv = Wv*Sx + N*bv, Sve = Wv*Sxe + bv*Seq.
// grid (4, B): block (cg,b) produces c in [64cg, 64cg+64); 4 lanes per output dot.
__global__ __launch_bounds__(256) void k_sv2(
        const float* __restrict__ Wv, const float* __restrict__ bv,
        const float* __restrict__ ws_ro, float* __restrict__ ws) {
    const int cg = blockIdx.x;             // 0..3
    const int b  = blockIdx.y;
    const int t  = threadIdx.x;
    __shared__ float sSx[C_DIM], sSxe[C_DIM];
    __shared__ float sSeq;
    float sx = 0.f, sxe = 0.f;
    #pragma unroll 8
    for (int nb = 0; nb < 64; ++nb) {      // coalesced across t
        sx  += ws_ro[PSX_OFF  + (size_t)(b * 64 + nb) * C_DIM + t];
        sxe += ws_ro[PSXE_OFF + (size_t)(b * 64 + nb) * C_DIM + t];
    }
    sSx[t] = sx; sSxe[t] = sxe;
    if (t < 64) {
        float se = wave_red_sum(ws_ro[PSEQ_OFF + b * 64 + t]);
        if (t == 0) sSeq = se;
    }
    __syncthreads();
    const int cl = t >> 2, s = t & 3;
    const int c  = cg * 64 + cl;
    const float4* wr = (const float4*)(Wv + (size_t)c * C_DIM + 64 * s);
    float sv = 0.f, sve = 0.f;
    #pragma unroll
    for (int i = 0; i < 16; ++i) {
        float4 wv4 = wr[i];
        const int base = 64 * s + 4 * i;
        sv  = fmaf(wv4.x, sSx[base],     sv);
        sv  = fmaf(wv4.y, sSx[base + 1], sv);
        sv  = fmaf(wv4.z, sSx[base + 2], sv);
        sv  = fmaf(wv4.w, sSx[base + 3], sv);
        sve = fmaf(wv4.x, sSxe[base],     sve);
        sve = fmaf(wv4.y, sSxe[base + 1], sve);
        sve = fmaf(wv4.z, sSxe[base + 2], sve);
        sve = fmaf(wv4.w, sSxe[base + 3], sve);
    }
    sv  += __shfl_down(sv, 2, 64);  sv  += __shfl_down(sv, 1, 64);
    sve += __shfl_down(sve, 2, 64); sve += __shfl_down(sve, 1, 64);
    if (s == 0) {
        ws[SV_OFF  + b * C_DIM + c] = sv + (float)N_DIM * bv[c];
        ws[SVE_OFF + b * C_DIM + c] = sve + bv[c] * sSeq;
    }
}

// KC: out[b,c,m] = ginv*Sve[b,c] + ginv*Sv[b,c]*ek[b,m] + x[b,c,m]
__global__ __launch_bounds__(256) void k_out(
        const float* __restrict__ x, const float* __restrict__ ws,
        const float* __restrict__ gamma, float* __restrict__ out) {
    const float ginv = gamma[0] / (float)N_DIM;
    const size_t total4 = (size_t)B_DIM * C_DIM * N_DIM / 4;
    for (size_t i = (size_t)blockIdx.x * blockDim.x + threadIdx.x; i < total4;
         i += (size_t)gridDim.x * blockDim.x) {
        const size_t e = i * 4;
        const int m  = (int)(e & (N_DIM - 1));
        const int bc = (int)(e >> 12);
        const int b  = bc >> 8;
        const float4 xv  = ((const float4*)x)[i];
        const float4 ekv = *(const float4*)(ws + EK_OFF + (size_t)b * N_DIM + m);
        const float t1 = ws[SV_OFF  + bc] * ginv;
        const float t2 = ws[SVE_OFF + bc] * ginv;
        float4 o;
        o.x = fmaf(ekv.x, t1, t2) + xv.x;
        o.y = fmaf(ekv.y, t1, t2) + xv.y;
        o.z = fmaf(ekv.z, t1, t2) + xv.z;
        o.w = fmaf(ekv.w, t1, t2) + xv.w;
        ((float4*)out)[i] = o;
    }
}

extern "C" void kernel_launch(void* const* d_in, const int* in_sizes, int n_in,
                              void* d_out, int out_size, void* d_ws, size_t ws_size,
                              hipStream_t stream) {
    const float* x     = (const float*)d_in[0];
    const float* Wq    = (const float*)d_in[1];
    const float* bq    = (const float*)d_in[2];
    const float* Wk    = (const float*)d_in[3];
    const float* bk    = (const float*)d_in[4];
    const float* Wc    = (const float*)d_in[5];
    const float* Wv    = (const float*)d_in[6];
    const float* bv    = (const float*)d_in[7];
    const float* gamma = (const float*)d_in[8];
    float* out = (float*)d_out;
    float* ws  = (float*)d_ws;

    dim3 gA(N_DIM / 64, B_DIM);            // 64 x 4 = 256 blocks
    k_fuse<<<gA, 256, 0, stream>>>(x, Wq, bq, Wk, bk, Wc, ws);

    dim3 gB(4, B_DIM);                     // 16 blocks
    k_sv2<<<gB, 256, 0, stream>>>(Wv, bv, ws, ws);

    k_out<<<4096, 256, 0, stream>>>(x, ws, gamma, out);
}